// Round 1
// baseline (701.485 us; speedup 1.0000x reference)
//
#include <hip/hip_runtime.h>

// KMeans assignment: N=262144 points, K=1024 centers, D=64, fp32 in, int32 argmin out.
// dist[n,k] = |x_norm[n] - 2*dot(x[n],c[k]) + c_norm[k]|, out[n] = argmin_k.
// Round 0: fp32 vector-ALU baseline (no fp32 MFMA on CDNA4). Compute-bound:
// 34.36 GFLOP @ 157.3 TF => ~218us floor.

#define N_PTS 262144
#define K_CTR 1024
#define DIM   64
#define TK    128   // centers per LDS tile: 128*64*4B = 32 KiB -> 4 blocks/CU

__global__ void cn_kernel(const float* __restrict__ centers, float* __restrict__ cn) {
    int k = blockIdx.x * blockDim.x + threadIdx.x;
    if (k >= K_CTR) return;
    const float4* c = reinterpret_cast<const float4*>(centers + (size_t)k * DIM);
    float s0 = 0.f, s1 = 0.f, s2 = 0.f, s3 = 0.f;
#pragma unroll
    for (int j = 0; j < DIM / 4; ++j) {
        float4 v = c[j];
        s0 = fmaf(v.x, v.x, s0);
        s1 = fmaf(v.y, v.y, s1);
        s2 = fmaf(v.z, v.z, s2);
        s3 = fmaf(v.w, v.w, s3);
    }
    cn[k] = (s0 + s1) + (s2 + s3);
}

__launch_bounds__(256, 4)
__global__ void assign_kernel(const float* __restrict__ x,
                              const float* __restrict__ centers,
                              const float* __restrict__ cn,
                              int* __restrict__ out) {
    __shared__ float ldsC[TK * DIM];   // 32 KiB
    __shared__ float ldsN[TK];

    const int tid = threadIdx.x;
    const int p = blockIdx.x * 256 + tid;

    // Load this thread's point into registers (16 x float4 = 64 VGPRs).
    const float4* xr = reinterpret_cast<const float4*>(x + (size_t)p * DIM);
    float4 xv[16];
    float xn0 = 0.f, xn1 = 0.f, xn2 = 0.f, xn3 = 0.f;
#pragma unroll
    for (int j = 0; j < 16; ++j) {
        float4 v = xr[j];
        xv[j] = v;
        xn0 = fmaf(v.x, v.x, xn0);
        xn1 = fmaf(v.y, v.y, xn1);
        xn2 = fmaf(v.z, v.z, xn2);
        xn3 = fmaf(v.w, v.w, xn3);
    }
    const float xn = (xn0 + xn1) + (xn2 + xn3);

    float bestv = 3.4e38f;
    int best = 0;

#pragma unroll 1
    for (int t = 0; t < K_CTR / TK; ++t) {
        __syncthreads();  // protect previous tile's readers
        // Stage TK centers: TK*DIM/4 = 2048 float4 across 256 threads -> 8 each.
        const float4* cg = reinterpret_cast<const float4*>(centers + (size_t)t * TK * DIM);
        float4* cl = reinterpret_cast<float4*>(ldsC);
#pragma unroll
        for (int j = 0; j < (TK * DIM / 4) / 256; ++j)
            cl[j * 256 + tid] = cg[j * 256 + tid];
        if (tid < TK) ldsN[tid] = cn[t * TK + tid];
        __syncthreads();

        for (int k = 0; k < TK; ++k) {
            const float4* cv = reinterpret_cast<const float4*>(ldsC + k * DIM);
            // 4 independent accumulator chains (ILP), 16 FMAs each.
            float a0 = 0.f, a1 = 0.f, a2 = 0.f, a3 = 0.f;
#pragma unroll
            for (int j = 0; j < 16; ++j) {
                float4 c4 = cv[j];
                a0 = fmaf(xv[j].x, c4.x, a0);
                a1 = fmaf(xv[j].y, c4.y, a1);
                a2 = fmaf(xv[j].z, c4.z, a2);
                a3 = fmaf(xv[j].w, c4.w, a3);
            }
            float dot = (a0 + a1) + (a2 + a3);
            float dist = fabsf(fmaf(-2.f, dot, xn + ldsN[k]));
            if (dist < bestv) {  // strict '<' keeps lowest index on ties (argmin semantics)
                bestv = dist;
                best = t * TK + k;
            }
        }
    }

    out[p] = best;
}

extern "C" void kernel_launch(void* const* d_in, const int* in_sizes, int n_in,
                              void* d_out, int out_size, void* d_ws, size_t ws_size,
                              hipStream_t stream) {
    const float* x = (const float*)d_in[0];
    const float* centers = (const float*)d_in[1];
    int* out = (int*)d_out;
    float* cn = (float*)d_ws;  // K_CTR floats = 4 KiB scratch

    cn_kernel<<<(K_CTR + 255) / 256, 256, 0, stream>>>(centers, cn);
    assign_kernel<<<N_PTS / 256, 256, 0, stream>>>(x, centers, cn, out);
}

// Round 2
// 387.949 us; speedup vs baseline: 1.8082x; 1.8082x over previous
//
#include <hip/hip_runtime.h>
#include <float.h>

// KMeans assign: N=262144, K=1024, D=64, fp32 in, int32 argmin out.
// Round 2: bf16x2-split MFMA GEMM (3 passes: hh, hl, lh) + second-best gap
// tracking; points with approx gap < TAU get exact fp32 recompute (refine
// kernel bit-identical to round-1 fp32 path, which matched np absmax=0).
// Useful 34.4 GFLOP -> 103 GFLOP bf16 MFMA @ ~2 PF => ~50-70us assign.

#define N_PTS 262144
#define K_CTR 1024
#define DIM   64
#define TAU   0.0625f   // >= 20x worst-case bf16x2 dist error (~3e-3)

typedef __attribute__((ext_vector_type(8))) short  short8;
typedef __attribute__((ext_vector_type(8))) __bf16 bf16x8;
typedef __attribute__((ext_vector_type(4))) float  f32x4;

union FragU { short8 s; bf16x8 b; };

static __device__ __forceinline__ unsigned short bfbits(__bf16 h) {
    return __builtin_bit_cast(unsigned short, h);
}

// ---------------- prep: centers_norm + zero refine counter ----------------
__global__ void prep_kernel(const float* __restrict__ centers,
                            float* __restrict__ cn, int* __restrict__ counter) {
    int k = blockIdx.x * 256 + threadIdx.x;
    if (k == 0) *counter = 0;
    if (k < K_CTR) {
        const float4* c = reinterpret_cast<const float4*>(centers + (size_t)k * DIM);
        float s0 = 0.f, s1 = 0.f, s2 = 0.f, s3 = 0.f;
#pragma unroll
        for (int j = 0; j < 16; ++j) {
            float4 v = c[j];
            s0 = fmaf(v.x, v.x, s0); s1 = fmaf(v.y, v.y, s1);
            s2 = fmaf(v.z, v.z, s2); s3 = fmaf(v.w, v.w, s3);
        }
        cn[k] = (s0 + s1) + (s2 + s3);
    }
}

// ---------------- main: MFMA assign with gap flagging ----------------
// Block = 256 thr = 4 waves; block handles 256 points (64/wave, 4 col-blocks
// of 16). Centers staged 256-at-a-time into LDS as frag-major bf16 hi/lo:
// slot(tile,kstep,lane) 16B each -> ds_read_b128 stride-1, conflict-free.
__launch_bounds__(256, 2)
__global__ void assign_mfma(const float* __restrict__ x,
                            const float* __restrict__ centers,
                            const float* __restrict__ cn,
                            int* __restrict__ out,
                            int* __restrict__ counter,
                            int* __restrict__ list, int cap) {
    __shared__ __align__(16) unsigned short lh[16 * 2 * 64 * 8]; // 32 KiB
    __shared__ __align__(16) unsigned short ll[16 * 2 * 64 * 8]; // 32 KiB

    const int tid  = threadIdx.x;
    const int lane = tid & 63;
    const int g    = lane >> 4;   // k-group 0..3
    const int lr   = lane & 15;   // row/col within 16
    const int pbase = blockIdx.x * 256 + (tid >> 6) * 64;

    // ---- B fragments (points) in registers: bf16 hi/lo, [colblock][kstep]
    bf16x8 bh[4][2], bl[4][2];
    float xn[4];
#pragma unroll
    for (int cb = 0; cb < 4; ++cb) {
        const int p = pbase + cb * 16 + lr;
        const float* xr = x + (size_t)p * DIM + g * 8;
        float4 v0 = *reinterpret_cast<const float4*>(xr);
        float4 v1 = *reinterpret_cast<const float4*>(xr + 4);
        float4 v2 = *reinterpret_cast<const float4*>(xr + 32);
        float4 v3 = *reinterpret_cast<const float4*>(xr + 36);
        float vv[16] = {v0.x, v0.y, v0.z, v0.w, v1.x, v1.y, v1.z, v1.w,
                        v2.x, v2.y, v2.z, v2.w, v3.x, v3.y, v3.z, v3.w};
        float sq = 0.f;
#pragma unroll
        for (int j = 0; j < 16; ++j) {
            __bf16 hb = (__bf16)vv[j];
            float  rs = vv[j] - (float)hb;
            bh[cb][j >> 3][j & 7] = hb;
            bl[cb][j >> 3][j & 7] = (__bf16)rs;
            sq = fmaf(vv[j], vv[j], sq);
        }
        sq += __shfl_xor(sq, 16);   // sum the 4 k-quarters of this point
        sq += __shfl_xor(sq, 32);
        xn[cb] = sq;
    }

    float best[4], sec[4]; int bidx[4];
#pragma unroll
    for (int cb = 0; cb < 4; ++cb) { best[cb] = FLT_MAX; sec[cb] = FLT_MAX; bidx[cb] = 0; }

#pragma unroll 1
    for (int ct = 0; ct < 4; ++ct) {
        __syncthreads();
        // stage 256 centers -> frag-major bf16 hi/lo
        const float4* cg = reinterpret_cast<const float4*>(centers + (size_t)ct * 256 * DIM);
#pragma unroll
        for (int j = 0; j < 16; ++j) {
            int f4i = j * 256 + tid;
            float4 v = cg[f4i];
            int row = f4i >> 4, cg4 = f4i & 15;
            int s = cg4 >> 3, gg = (cg4 & 7) >> 1, half = cg4 & 1;
            int ui = (((row >> 4) * 2 + s) * 64 + gg * 16 + (row & 15)) * 8 + half * 4;
            __bf16 h0 = (__bf16)v.x, h1 = (__bf16)v.y, h2 = (__bf16)v.z, h3 = (__bf16)v.w;
            float r0 = v.x - (float)h0, r1 = v.y - (float)h1,
                  r2 = v.z - (float)h2, r3 = v.w - (float)h3;
            ushort4 hw, lw;
            hw.x = bfbits(h0); hw.y = bfbits(h1); hw.z = bfbits(h2); hw.w = bfbits(h3);
            lw.x = bfbits((__bf16)r0); lw.y = bfbits((__bf16)r1);
            lw.z = bfbits((__bf16)r2); lw.w = bfbits((__bf16)r3);
            *reinterpret_cast<ushort4*>(&lh[ui]) = hw;
            *reinterpret_cast<ushort4*>(&ll[ui]) = lw;
        }
        __syncthreads();

#pragma unroll 1
        for (int st = 0; st < 16; ++st) {
            FragU ah0, ah1, al0, al1;
            ah0.s = *(reinterpret_cast<const short8*>(lh) + (st * 2 + 0) * 64 + lane);
            ah1.s = *(reinterpret_cast<const short8*>(lh) + (st * 2 + 1) * 64 + lane);
            al0.s = *(reinterpret_cast<const short8*>(ll) + (st * 2 + 0) * 64 + lane);
            al1.s = *(reinterpret_cast<const short8*>(ll) + (st * 2 + 1) * 64 + lane);
            const float4 c4 = *reinterpret_cast<const float4*>(cn + ct * 256 + st * 16 + g * 4);
            const float cv[4] = {c4.x, c4.y, c4.z, c4.w};

            f32x4 acc[4];
#pragma unroll
            for (int cb = 0; cb < 4; ++cb) acc[cb] = (f32x4){0.f, 0.f, 0.f, 0.f};
            // 3 split passes x 2 k-steps, 4 independent col-block chains
#pragma unroll
            for (int cb = 0; cb < 4; ++cb)
                acc[cb] = __builtin_amdgcn_mfma_f32_16x16x32_bf16(ah0.b, bh[cb][0], acc[cb], 0, 0, 0);
#pragma unroll
            for (int cb = 0; cb < 4; ++cb)
                acc[cb] = __builtin_amdgcn_mfma_f32_16x16x32_bf16(ah0.b, bl[cb][0], acc[cb], 0, 0, 0);
#pragma unroll
            for (int cb = 0; cb < 4; ++cb)
                acc[cb] = __builtin_amdgcn_mfma_f32_16x16x32_bf16(al0.b, bh[cb][0], acc[cb], 0, 0, 0);
#pragma unroll
            for (int cb = 0; cb < 4; ++cb)
                acc[cb] = __builtin_amdgcn_mfma_f32_16x16x32_bf16(ah1.b, bh[cb][1], acc[cb], 0, 0, 0);
#pragma unroll
            for (int cb = 0; cb < 4; ++cb)
                acc[cb] = __builtin_amdgcn_mfma_f32_16x16x32_bf16(ah1.b, bl[cb][1], acc[cb], 0, 0, 0);
#pragma unroll
            for (int cb = 0; cb < 4; ++cb)
                acc[cb] = __builtin_amdgcn_mfma_f32_16x16x32_bf16(al1.b, bh[cb][1], acc[cb], 0, 0, 0);

            const int ibase = ct * 256 + st * 16 + g * 4;
#pragma unroll
            for (int cb = 0; cb < 4; ++cb) {
#pragma unroll
                for (int r = 0; r < 4; ++r) {
                    float d  = fmaf(-2.f, acc[cb][r], xn[cb]) + cv[r];
                    float ad = fabsf(d);
                    bool  c  = ad < best[cb];
                    sec[cb]  = fminf(sec[cb], fmaxf(ad, best[cb]));
                    best[cb] = c ? ad : best[cb];
                    bidx[cb] = c ? (ibase + r) : bidx[cb];
                }
            }
        }
    }

    // merge the 4 k-groups (disjoint center subsets, same point)
#pragma unroll
    for (int cb = 0; cb < 4; ++cb) {
        float b = best[cb], sc = sec[cb]; int ix = bidx[cb];
#pragma unroll
        for (int off = 16; off <= 32; off <<= 1) {
            float ob = __shfl_xor(b, off);
            float os = __shfl_xor(sc, off);
            int   oi = __shfl_xor(ix, off);
            sc = fminf(fminf(sc, os), fmaxf(b, ob));
            bool take = (ob < b) || (ob == b && oi < ix);  // tie -> lowest index
            b  = take ? ob : b;
            ix = take ? oi : ix;
        }
        if (g == 0) {
            const int p = pbase + cb * 16 + lr;
            out[p] = ix;
            if (sc - b < TAU) {
                int sl = atomicAdd(counter, 1);
                if (sl < cap) list[sl] = p;
            }
        }
    }
}

// ---------------- refine: exact fp32 recompute for flagged points ----------
// One wave per point; bit-identical arithmetic to the round-1 fp32 kernel
// (which matched the np reference with absmax=0).
__global__ void refine_kernel(const float* __restrict__ x,
                              const float* __restrict__ centers,
                              const float* __restrict__ cn,
                              const int* __restrict__ list,
                              const int* __restrict__ counter,
                              int* __restrict__ out, int cap) {
    int cnt = *counter; if (cnt > cap) cnt = cap;
    const int lane = threadIdx.x & 63;
    const int wid  = (blockIdx.x * blockDim.x + threadIdx.x) >> 6;
    const int nw   = (gridDim.x * blockDim.x) >> 6;
    for (int i = wid; i < cnt; i += nw) {
        const int p = list[i];
        const float4* xr = reinterpret_cast<const float4*>(x + (size_t)p * DIM);
        float4 xv[16];
        float xn0 = 0.f, xn1 = 0.f, xn2 = 0.f, xn3 = 0.f;
#pragma unroll
        for (int j = 0; j < 16; ++j) {
            float4 v = xr[j]; xv[j] = v;
            xn0 = fmaf(v.x, v.x, xn0); xn1 = fmaf(v.y, v.y, xn1);
            xn2 = fmaf(v.z, v.z, xn2); xn3 = fmaf(v.w, v.w, xn3);
        }
        const float xnv = (xn0 + xn1) + (xn2 + xn3);
        float bestv = 3.4e38f; int bi = 0;
#pragma unroll 1
        for (int t = 0; t < 16; ++t) {           // lane covers k = lane*16 .. lane*16+15
            const int k = lane * 16 + t;
            const float4* cr = reinterpret_cast<const float4*>(centers + (size_t)k * DIM);
            float a0 = 0.f, a1 = 0.f, a2 = 0.f, a3 = 0.f;
#pragma unroll
            for (int j = 0; j < 16; ++j) {
                float4 c4 = cr[j];
                a0 = fmaf(xv[j].x, c4.x, a0); a1 = fmaf(xv[j].y, c4.y, a1);
                a2 = fmaf(xv[j].z, c4.z, a2); a3 = fmaf(xv[j].w, c4.w, a3);
            }
            float dot  = (a0 + a1) + (a2 + a3);
            float dist = fabsf(fmaf(-2.f, dot, xnv + cn[k]));
            if (dist < bestv) { bestv = dist; bi = k; }
        }
#pragma unroll
        for (int off = 1; off < 64; off <<= 1) {
            float ob = __shfl_xor(bestv, off);
            int   oi = __shfl_xor(bi, off);
            bool take = (ob < bestv) || (ob == bestv && oi < bi);
            bestv = take ? ob : bestv;
            bi    = take ? oi : bi;
        }
        if (lane == 0) out[p] = bi;
    }
}

// ---------------- fallback: round-1 pure fp32 path ----------------
__global__ void cn_kernel(const float* __restrict__ centers, float* __restrict__ cn) {
    int k = blockIdx.x * blockDim.x + threadIdx.x;
    if (k >= K_CTR) return;
    const float4* c = reinterpret_cast<const float4*>(centers + (size_t)k * DIM);
    float s0 = 0.f, s1 = 0.f, s2 = 0.f, s3 = 0.f;
#pragma unroll
    for (int j = 0; j < DIM / 4; ++j) {
        float4 v = c[j];
        s0 = fmaf(v.x, v.x, s0); s1 = fmaf(v.y, v.y, s1);
        s2 = fmaf(v.z, v.z, s2); s3 = fmaf(v.w, v.w, s3);
    }
    cn[k] = (s0 + s1) + (s2 + s3);
}

#define TK 128
__launch_bounds__(256, 4)
__global__ void assign_fp32(const float* __restrict__ x,
                            const float* __restrict__ centers,
                            const float* __restrict__ cn,
                            int* __restrict__ out) {
    __shared__ float ldsC[TK * DIM];
    __shared__ float ldsN[TK];
    const int tid = threadIdx.x;
    const int p = blockIdx.x * 256 + tid;
    const float4* xr = reinterpret_cast<const float4*>(x + (size_t)p * DIM);
    float4 xv[16];
    float xn0 = 0.f, xn1 = 0.f, xn2 = 0.f, xn3 = 0.f;
#pragma unroll
    for (int j = 0; j < 16; ++j) {
        float4 v = xr[j]; xv[j] = v;
        xn0 = fmaf(v.x, v.x, xn0); xn1 = fmaf(v.y, v.y, xn1);
        xn2 = fmaf(v.z, v.z, xn2); xn3 = fmaf(v.w, v.w, xn3);
    }
    const float xn = (xn0 + xn1) + (xn2 + xn3);
    float bestv = 3.4e38f; int best = 0;
#pragma unroll 1
    for (int t = 0; t < K_CTR / TK; ++t) {
        __syncthreads();
        const float4* cg = reinterpret_cast<const float4*>(centers + (size_t)t * TK * DIM);
        float4* cl = reinterpret_cast<float4*>(ldsC);
#pragma unroll
        for (int j = 0; j < (TK * DIM / 4) / 256; ++j)
            cl[j * 256 + tid] = cg[j * 256 + tid];
        if (tid < TK) ldsN[tid] = cn[t * TK + tid];
        __syncthreads();
        for (int k = 0; k < TK; ++k) {
            const float4* cv = reinterpret_cast<const float4*>(ldsC + k * DIM);
            float a0 = 0.f, a1 = 0.f, a2 = 0.f, a3 = 0.f;
#pragma unroll
            for (int j = 0; j < 16; ++j) {
                float4 c4 = cv[j];
                a0 = fmaf(xv[j].x, c4.x, a0); a1 = fmaf(xv[j].y, c4.y, a1);
                a2 = fmaf(xv[j].z, c4.z, a2); a3 = fmaf(xv[j].w, c4.w, a3);
            }
            float dot = (a0 + a1) + (a2 + a3);
            float dist = fabsf(fmaf(-2.f, dot, xn + ldsN[k]));
            if (dist < bestv) { bestv = dist; best = t * TK + k; }
        }
    }
    out[p] = best;
}

extern "C" void kernel_launch(void* const* d_in, const int* in_sizes, int n_in,
                              void* d_out, int out_size, void* d_ws, size_t ws_size,
                              hipStream_t stream) {
    const float* x = (const float*)d_in[0];
    const float* centers = (const float*)d_in[1];
    int* out = (int*)d_out;
    float* cn = (float*)d_ws;
    int* counter = (int*)((char*)d_ws + 4096);
    int* list = (int*)((char*)d_ws + 4096 + 256);

    const size_t min_ws = 4096 + 256 + sizeof(int) * 65536;
    if (ws_size >= min_ws) {
        size_t avail = (ws_size - 4096 - 256) / sizeof(int);
        int cap = (int)(avail < (size_t)N_PTS ? avail : (size_t)N_PTS);
        prep_kernel<<<4, 256, 0, stream>>>(centers, cn, counter);
        assign_mfma<<<N_PTS / 256, 256, 0, stream>>>(x, centers, cn, out, counter, list, cap);
        refine_kernel<<<128, 256, 0, stream>>>(x, centers, cn, list, counter, out, cap);
    } else {
        cn_kernel<<<4, 256, 0, stream>>>(centers, cn);
        assign_fp32<<<N_PTS / 256, 256, 0, stream>>>(x, centers, cn, out);
    }
}

// Round 3
// 158.635 us; speedup vs baseline: 4.4220x; 2.4455x over previous
//
#include <hip/hip_runtime.h>
#include <float.h>

// KMeans assign: N=262144, K=1024, D=64, fp32 in, int32 argmin out.
// Round 3: bf16x2-split MFMA (3 passes) with key-packed argmin epilogue
// (acc init = -(xn+cn)/2 -> acc = -dist/2 < 0; uint bits monotone in dist;
// key = trunc-bits | center-idx -> umin = argmin with first-index ties).
// Gap-flagged points (TAU=0.06) recomputed by refine2: LDS-tiled, lane=center,
// EXACT round-1 fp32 summation order (empirically absmax=0 vs np).

#define N_PTS 262144
#define K_CTR 1024
#define DIM   64
#define CTILE 128        // centers per assign LDS tile (32 KiB hi+lo)
#define TAU_DIST 0.06f   // flag threshold in dist units (worst err ~8e-3 + 2 quanta 1.6e-2)

typedef __attribute__((ext_vector_type(8))) short  short8;
typedef __attribute__((ext_vector_type(8))) __bf16 bf16x8;
typedef __attribute__((ext_vector_type(4))) float  f32x4;

union FragU { short8 s; bf16x8 b; };

static __device__ __forceinline__ unsigned short bfbits(__bf16 h) {
    return __builtin_bit_cast(unsigned short, h);
}

// ---------------- prep: centers_norm (round-1 chain order) + zero counter ----
__global__ void prep_kernel(const float* __restrict__ centers,
                            float* __restrict__ cn, int* __restrict__ counter) {
    int k = blockIdx.x * 256 + threadIdx.x;
    if (k == 0) *counter = 0;
    if (k < K_CTR) {
        const float4* c = reinterpret_cast<const float4*>(centers + (size_t)k * DIM);
        float s0 = 0.f, s1 = 0.f, s2 = 0.f, s3 = 0.f;
#pragma unroll
        for (int j = 0; j < 16; ++j) {
            float4 v = c[j];
            s0 = fmaf(v.x, v.x, s0); s1 = fmaf(v.y, v.y, s1);
            s2 = fmaf(v.z, v.z, s2); s3 = fmaf(v.w, v.w, s3);
        }
        cn[k] = (s0 + s1) + (s2 + s3);
    }
}

// ---------------- main: MFMA assign, key-packed argmin ----------------
__launch_bounds__(256, 3)
__global__ void assign_mfma(const float* __restrict__ x,
                            const float* __restrict__ centers,
                            const float* __restrict__ cn,
                            int* __restrict__ out,
                            int* __restrict__ counter,
                            int* __restrict__ list, int cap) {
    __shared__ __align__(16) unsigned short lh[8 * 2 * 64 * 8]; // 16 KiB
    __shared__ __align__(16) unsigned short ll[8 * 2 * 64 * 8]; // 16 KiB

    const int tid  = threadIdx.x;
    const int lane = tid & 63;
    const int g    = lane >> 4;   // k-group 0..3
    const int lr   = lane & 15;   // point-col within 16
    const int pbase = blockIdx.x * 256 + (tid >> 6) * 64;

    // ---- B fragments (points): bf16 hi/lo, [colblock][kstep]; mxn = -xn/2
    bf16x8 bh[4][2], bl[4][2];
    float mxn[4];
#pragma unroll
    for (int cb = 0; cb < 4; ++cb) {
        const int p = pbase + cb * 16 + lr;
        const float* xr = x + (size_t)p * DIM + g * 8;
        float4 v0 = *reinterpret_cast<const float4*>(xr);
        float4 v1 = *reinterpret_cast<const float4*>(xr + 4);
        float4 v2 = *reinterpret_cast<const float4*>(xr + 32);
        float4 v3 = *reinterpret_cast<const float4*>(xr + 36);
        float vv[16] = {v0.x, v0.y, v0.z, v0.w, v1.x, v1.y, v1.z, v1.w,
                        v2.x, v2.y, v2.z, v2.w, v3.x, v3.y, v3.z, v3.w};
        float sq = 0.f;
#pragma unroll
        for (int j = 0; j < 16; ++j) {
            __bf16 hb = (__bf16)vv[j];
            float  rs = vv[j] - (float)hb;
            bh[cb][j >> 3][j & 7] = hb;
            bl[cb][j >> 3][j & 7] = (__bf16)rs;
            sq = fmaf(vv[j], vv[j], sq);
        }
        sq += __shfl_xor(sq, 16);
        sq += __shfl_xor(sq, 32);
        mxn[cb] = -0.5f * sq;
    }

    unsigned int best[4], sec[4];
#pragma unroll
    for (int cb = 0; cb < 4; ++cb) { best[cb] = 0xFFFFFFFFu; sec[cb] = 0xFFFFFFFFu; }

#pragma unroll 1
    for (int ct = 0; ct < K_CTR / CTILE; ++ct) {
        __syncthreads();
        // stage CTILE centers -> frag-major bf16 hi/lo (8 float4 per thread)
        const float4* cg = reinterpret_cast<const float4*>(centers + (size_t)ct * CTILE * DIM);
#pragma unroll
        for (int j = 0; j < (CTILE * 16) / 256; ++j) {
            int f4i = j * 256 + tid;
            float4 v = cg[f4i];
            int row = f4i >> 4, c4 = f4i & 15;
            int s = c4 >> 3, gg = (c4 & 7) >> 1, half = c4 & 1;
            int ui = (((row >> 4) * 2 + s) * 64 + gg * 16 + (row & 15)) * 8 + half * 4;
            __bf16 h0 = (__bf16)v.x, h1 = (__bf16)v.y, h2 = (__bf16)v.z, h3 = (__bf16)v.w;
            float r0 = v.x - (float)h0, r1 = v.y - (float)h1,
                  r2 = v.z - (float)h2, r3 = v.w - (float)h3;
            ushort4 hw, lw;
            hw.x = bfbits(h0); hw.y = bfbits(h1); hw.z = bfbits(h2); hw.w = bfbits(h3);
            lw.x = bfbits((__bf16)r0); lw.y = bfbits((__bf16)r1);
            lw.z = bfbits((__bf16)r2); lw.w = bfbits((__bf16)r3);
            *reinterpret_cast<ushort4*>(&lh[ui]) = hw;
            *reinterpret_cast<ushort4*>(&ll[ui]) = lw;
        }
        __syncthreads();

#pragma unroll 1
        for (int st = 0; st < CTILE / 16; ++st) {
            FragU ah0, ah1, al0, al1;
            ah0.s = *(reinterpret_cast<const short8*>(lh) + (st * 2 + 0) * 64 + lane);
            ah1.s = *(reinterpret_cast<const short8*>(lh) + (st * 2 + 1) * 64 + lane);
            al0.s = *(reinterpret_cast<const short8*>(ll) + (st * 2 + 0) * 64 + lane);
            al1.s = *(reinterpret_cast<const short8*>(ll) + (st * 2 + 1) * 64 + lane);
            const float4 c4 = *reinterpret_cast<const float4*>(cn + ct * CTILE + st * 16 + g * 4);
            const float cv[4] = {c4.x, c4.y, c4.z, c4.w};

            // acc init = -(xn + cn)/2  ->  acc_final = -dist/2 (always < 0)
            f32x4 acc[4];
#pragma unroll
            for (int cb = 0; cb < 4; ++cb) {
#pragma unroll
                for (int r = 0; r < 4; ++r)
                    acc[cb][r] = fmaf(-0.5f, cv[r], mxn[cb]);
            }
#pragma unroll
            for (int cb = 0; cb < 4; ++cb)
                acc[cb] = __builtin_amdgcn_mfma_f32_16x16x32_bf16(ah0.b, bh[cb][0], acc[cb], 0, 0, 0);
#pragma unroll
            for (int cb = 0; cb < 4; ++cb)
                acc[cb] = __builtin_amdgcn_mfma_f32_16x16x32_bf16(ah0.b, bl[cb][0], acc[cb], 0, 0, 0);
#pragma unroll
            for (int cb = 0; cb < 4; ++cb)
                acc[cb] = __builtin_amdgcn_mfma_f32_16x16x32_bf16(al0.b, bh[cb][0], acc[cb], 0, 0, 0);
#pragma unroll
            for (int cb = 0; cb < 4; ++cb)
                acc[cb] = __builtin_amdgcn_mfma_f32_16x16x32_bf16(ah1.b, bh[cb][1], acc[cb], 0, 0, 0);
#pragma unroll
            for (int cb = 0; cb < 4; ++cb)
                acc[cb] = __builtin_amdgcn_mfma_f32_16x16x32_bf16(ah1.b, bl[cb][1], acc[cb], 0, 0, 0);
#pragma unroll
            for (int cb = 0; cb < 4; ++cb)
                acc[cb] = __builtin_amdgcn_mfma_f32_16x16x32_bf16(al1.b, bh[cb][1], acc[cb], 0, 0, 0);

            const unsigned int ibase = ct * CTILE + st * 16 + g * 4;
#pragma unroll
            for (int cb = 0; cb < 4; ++cb) {
#pragma unroll
                for (int pr = 0; pr < 2; ++pr) {
                    unsigned int ka = (__float_as_uint(acc[cb][pr * 2 + 0]) & 0xFFFFFC00u) | (ibase + pr * 2 + 0);
                    unsigned int kb = (__float_as_uint(acc[cb][pr * 2 + 1]) & 0xFFFFFC00u) | (ibase + pr * 2 + 1);
                    unsigned int lo = min(ka, kb), hi = max(ka, kb);
                    // sec = min(sec, med3(ka, kb, best_old)); best = min(best, lo)
                    sec[cb]  = min(sec[cb], max(lo, min(hi, best[cb])));
                    best[cb] = min(best[cb], lo);
                }
            }
        }
    }

    // merge the 4 disjoint k-groups per point
#pragma unroll
    for (int cb = 0; cb < 4; ++cb) {
        unsigned int b = best[cb], s = sec[cb];
#pragma unroll
        for (int off = 16; off <= 32; off <<= 1) {
            unsigned int ob = __shfl_xor(b, off);
            unsigned int os = __shfl_xor(s, off);
            s = min(min(s, os), max(b, ob));
            b = min(b, ob);
        }
        if (g == 0) {
            const int p = pbase + cb * 16 + lr;
            out[p] = (int)(b & 1023u);
            float bf = __uint_as_float(b & 0xFFFFFC00u);  // = -best_dist/2 (trunc)
            float sf = __uint_as_float(s & 0xFFFFFC00u);  // = -sec_dist/2  (trunc)
            if (2.f * (bf - sf) < TAU_DIST) {
                int sl = atomicAdd(counter, 1);
                if (sl < cap) list[sl] = p;
            }
        }
    }
}

// ---------------- refine2: exact fp32, round-1 chain order, LDS-tiled -------
// Block = 4 waves; 1 point/wave/round; lane = center within 64-row tile.
// LDS stride 65 -> read bank = (lane + col) % 32, 2-way alias (free).
__launch_bounds__(256, 2)
__global__ void refine2_kernel(const float* __restrict__ x,
                               const float* __restrict__ centers,
                               const float* __restrict__ cn,
                               const int* __restrict__ list,
                               const int* __restrict__ counter,
                               int* __restrict__ out, int cap) {
    __shared__ float ldsC[64 * 65];   // 16.6 KiB
    int cnt = *counter; if (cnt > cap) cnt = cap;
    const int tid  = threadIdx.x;
    const int wv   = tid >> 6;
    const int lane = tid & 63;

#pragma unroll 1
    for (int base = blockIdx.x * 4; base < cnt; base += gridDim.x * 4) {
        const int i = base + wv;
        const bool valid = (i < cnt);
        const int p = valid ? list[i] : 0;

        // x row (all lanes same row -> broadcast loads), round-1 chain order
        const float4* xr = reinterpret_cast<const float4*>(x + (size_t)p * DIM);
        float4 xv[16];
        float xn0 = 0.f, xn1 = 0.f, xn2 = 0.f, xn3 = 0.f;
#pragma unroll
        for (int j = 0; j < 16; ++j) {
            float4 v = xr[j]; xv[j] = v;
            xn0 = fmaf(v.x, v.x, xn0); xn1 = fmaf(v.y, v.y, xn1);
            xn2 = fmaf(v.z, v.z, xn2); xn3 = fmaf(v.w, v.w, xn3);
        }
        const float xnv = (xn0 + xn1) + (xn2 + xn3);

        float bestv = 3.4e38f; int bi = 0;
#pragma unroll 1
        for (int t = 0; t < 16; ++t) {            // 16 tiles x 64 centers
            __syncthreads();
            // stage tile: 4096 floats, 16 per thread, coalesced global reads
#pragma unroll
            for (int j = 0; j < 16; ++j) {
                int idx = j * 256 + tid;
                int row = idx >> 6, col = idx & 63;
                ldsC[row * 65 + col] = centers[((size_t)t * 64 + row) * DIM + col];
            }
            __syncthreads();
            if (valid) {
                const int k = t * 64 + lane;
                const float* cr = ldsC + lane * 65;
                float a0 = 0.f, a1 = 0.f, a2 = 0.f, a3 = 0.f;
#pragma unroll
                for (int jj = 0; jj < 16; ++jj) {
                    a0 = fmaf(xv[jj].x, cr[jj * 4 + 0], a0);
                    a1 = fmaf(xv[jj].y, cr[jj * 4 + 1], a1);
                    a2 = fmaf(xv[jj].z, cr[jj * 4 + 2], a2);
                    a3 = fmaf(xv[jj].w, cr[jj * 4 + 3], a3);
                }
                float dot  = (a0 + a1) + (a2 + a3);
                float dist = fabsf(fmaf(-2.f, dot, xnv + cn[k]));
                if (dist < bestv) { bestv = dist; bi = k; }
            }
        }
        // merge 64 lanes, first-index tie-break
#pragma unroll
        for (int off = 1; off < 64; off <<= 1) {
            float ob = __shfl_xor(bestv, off);
            int   oi = __shfl_xor(bi, off);
            bool take = (ob < bestv) || (ob == bestv && oi < bi);
            bestv = take ? ob : bestv;
            bi    = take ? oi : bi;
        }
        if (valid && lane == 0) out[p] = bi;
    }
}

// ---------------- fallback: round-1 pure fp32 path (ws too small) ----------
#define TK 128
__launch_bounds__(256, 4)
__global__ void assign_fp32(const float* __restrict__ x,
                            const float* __restrict__ centers,
                            const float* __restrict__ cn,
                            int* __restrict__ out) {
    __shared__ float ldsC[TK * DIM];
    __shared__ float ldsN[TK];
    const int tid = threadIdx.x;
    const int p = blockIdx.x * 256 + tid;
    const float4* xr = reinterpret_cast<const float4*>(x + (size_t)p * DIM);
    float4 xv[16];
    float xn0 = 0.f, xn1 = 0.f, xn2 = 0.f, xn3 = 0.f;
#pragma unroll
    for (int j = 0; j < 16; ++j) {
        float4 v = xr[j]; xv[j] = v;
        xn0 = fmaf(v.x, v.x, xn0); xn1 = fmaf(v.y, v.y, xn1);
        xn2 = fmaf(v.z, v.z, xn2); xn3 = fmaf(v.w, v.w, xn3);
    }
    const float xn = (xn0 + xn1) + (xn2 + xn3);
    float bestv = 3.4e38f; int best = 0;
#pragma unroll 1
    for (int t = 0; t < K_CTR / TK; ++t) {
        __syncthreads();
        const float4* cg = reinterpret_cast<const float4*>(centers + (size_t)t * TK * DIM);
        float4* cl = reinterpret_cast<float4*>(ldsC);
#pragma unroll
        for (int j = 0; j < (TK * DIM / 4) / 256; ++j)
            cl[j * 256 + tid] = cg[j * 256 + tid];
        if (tid < TK) ldsN[tid] = cn[t * TK + tid];
        __syncthreads();
        for (int k = 0; k < TK; ++k) {
            const float4* cv = reinterpret_cast<const float4*>(ldsC + k * DIM);
            float a0 = 0.f, a1 = 0.f, a2 = 0.f, a3 = 0.f;
#pragma unroll
            for (int j = 0; j < 16; ++j) {
                float4 c4 = cv[j];
                a0 = fmaf(xv[j].x, c4.x, a0); a1 = fmaf(xv[j].y, c4.y, a1);
                a2 = fmaf(xv[j].z, c4.z, a2); a3 = fmaf(xv[j].w, c4.w, a3);
            }
            float dot = (a0 + a1) + (a2 + a3);
            float dist = fabsf(fmaf(-2.f, dot, xn + ldsN[k]));
            if (dist < bestv) { bestv = dist; best = t * TK + k; }
        }
    }
    out[p] = best;
}

extern "C" void kernel_launch(void* const* d_in, const int* in_sizes, int n_in,
                              void* d_out, int out_size, void* d_ws, size_t ws_size,
                              hipStream_t stream) {
    const float* x = (const float*)d_in[0];
    const float* centers = (const float*)d_in[1];
    int* out = (int*)d_out;
    float* cn = (float*)d_ws;
    int* counter = (int*)((char*)d_ws + 4096);
    int* list = (int*)((char*)d_ws + 4096 + 256);

    const size_t min_ws = 4096 + 256 + sizeof(int) * 65536;
    if (ws_size >= min_ws) {
        size_t avail = (ws_size - 4096 - 256) / sizeof(int);
        int cap = (int)(avail < (size_t)N_PTS ? avail : (size_t)N_PTS);
        prep_kernel<<<4, 256, 0, stream>>>(centers, cn, counter);
        assign_mfma<<<N_PTS / 256, 256, 0, stream>>>(x, centers, cn, out, counter, list, cap);
        refine2_kernel<<<512, 256, 0, stream>>>(x, centers, cn, list, counter, out, cap);
    } else {
        prep_kernel<<<4, 256, 0, stream>>>(centers, cn, counter);
        assign_fp32<<<N_PTS / 256, 256, 0, stream>>>(x, centers, cn, out);
    }
}